// Round 4
// baseline (127.483 us; speedup 1.0000x reference)
//
#include <hip/hip_runtime.h>
#include <hip/hip_cooperative_groups.h>

namespace cg = cooperative_groups;

#define BATCH 64
#define NPTS  4096
#define NFRAMES 100
#define BLOCK 256
#define PPT 2                          // points per thread
#define KSPAN (BLOCK * PPT)            // 512
#define NBLK_X (NPTS / KSPAN)          // 8
#define NBLOCKS (BATCH * NBLK_X)       // 512
#define EPS_DIST_F 1e-8f

// R4: single cooperative kernel. R3's atomic-ticket fusion regressed (+16us:
// memset dispatch + 512 blocks x 3 device RMWs + threadfence on ONE cacheline
// = serialized cross-XCD storm). This version: each block writes its partial
// pair to DISTINCT ws slots (written-before-read -> no init, no memset),
// grid.sync() (one ROCm-managed arrival per block), then block 0 reduces the
// 512 pairs with the exact same summation order as the old fape_final
// (bitwise-identical output). One dispatch total vs R1's two.
//
// Math note: reference rotates diff by an orthonormal frame before the norm;
// rotation preserves the 2-norm, so distance = ||(pred_k - true_k) -
// (pred_f - true_f)||. Frame origins are the first NFRAMES points.
// Co-residency: 512 blocks x 256 thr = 2 blocks/CU @ ~16 VGPR, 1.5KB LDS.
__global__ __launch_bounds__(BLOCK) void fape_coop(
    const float* __restrict__ pred,
    const float* __restrict__ truec,
    const float* __restrict__ mask,
    float* __restrict__ ws,            // [NBLOCKS*2] partial (num, den)
    float* __restrict__ out)
{
    __shared__ __align__(16) float sfx[NFRAMES];
    __shared__ __align__(16) float sfy[NFRAMES];
    __shared__ __align__(16) float sfz[NFRAMES];

    const int b  = blockIdx.y;
    const int k0 = blockIdx.x * KSPAN + threadIdx.x;
    const int k1 = k0 + BLOCK;
    const int bid = b * NBLK_X + blockIdx.x;

    const float* __restrict__ pb = pred  + (size_t)b * NPTS * 3;
    const float* __restrict__ tb = truec + (size_t)b * NPTS * 3;

    // Issue the point loads FIRST: their HBM latency drains during the
    // staging stores + barrier (compiler waits vmcnt(0) before s_barrier).
    const float p0x = pb[3 * k0 + 0], p0y = pb[3 * k0 + 1], p0z = pb[3 * k0 + 2];
    const float t0x = tb[3 * k0 + 0], t0y = tb[3 * k0 + 1], t0z = tb[3 * k0 + 2];
    const float p1x = pb[3 * k1 + 0], p1y = pb[3 * k1 + 1], p1z = pb[3 * k1 + 2];
    const float t1x = tb[3 * k1 + 0], t1y = tb[3 * k1 + 1], t1z = tb[3 * k1 + 2];

    // Stage frame deltas (origins f = coords[:, :-2] -> first 100 points).
    if (threadIdx.x < NFRAMES) {
        const int t = threadIdx.x;
        sfx[t] = pb[3 * t + 0] - tb[3 * t + 0];
        sfy[t] = pb[3 * t + 1] - tb[3 * t + 1];
        sfz[t] = pb[3 * t + 2] - tb[3 * t + 2];
    }
    __syncthreads();

    const float d0x = p0x - t0x, d0y = p0y - t0y, d0z = p0z - t0z;
    const float d1x = p1x - t1x, d1y = p1y - t1y, d1z = p1z - t1z;

    float acc0 = 0.0f, acc1 = 0.0f;

#define EVAL(DX, DY, DZ, FX, FY, FZ, ACC) do {                                  \
        const float ex_ = (DX) - (FX);                                          \
        const float ey_ = (DY) - (FY);                                          \
        const float ez_ = (DZ) - (FZ);                                          \
        const float s_  = __builtin_fmaf(ex_, ex_,                              \
                          __builtin_fmaf(ey_, ey_,                              \
                          __builtin_fmaf(ez_, ez_, EPS_DIST_F)));               \
        (ACC) += fminf(__builtin_amdgcn_sqrtf(s_), 10.0f);                      \
    } while (0)

#pragma unroll 2
    for (int f = 0; f < NFRAMES; f += 4) {
        const float4 fx = *(const float4*)&sfx[f];
        const float4 fy = *(const float4*)&sfy[f];
        const float4 fz = *(const float4*)&sfz[f];

        EVAL(d0x, d0y, d0z, fx.x, fy.x, fz.x, acc0);
        EVAL(d1x, d1y, d1z, fx.x, fy.x, fz.x, acc1);
        EVAL(d0x, d0y, d0z, fx.y, fy.y, fz.y, acc0);
        EVAL(d1x, d1y, d1z, fx.y, fy.y, fz.y, acc1);
        EVAL(d0x, d0y, d0z, fx.z, fy.z, fz.z, acc0);
        EVAL(d1x, d1y, d1z, fx.z, fy.z, fz.z, acc1);
        EVAL(d0x, d0y, d0z, fx.w, fy.w, fz.w, acc0);
        EVAL(d1x, d1y, d1z, fx.w, fy.w, fz.w, acc1);
    }
#undef EVAL

    const float m0 = mask[(size_t)b * NPTS + k0];
    const float m1 = mask[(size_t)b * NPTS + k1];
    float num = (acc0 * m0 + acc1 * m1) * 0.1f;
    float den = m0 + m1;

    // Wave-64 shuffle reduction.
    for (int off = 32; off > 0; off >>= 1) {
        num += __shfl_down(num, off, 64);
        den += __shfl_down(den, off, 64);
    }

    __shared__ float snum[BLOCK / 64];
    __shared__ float sden[BLOCK / 64];
    const int wave = threadIdx.x >> 6;
    const int lane = threadIdx.x & 63;
    if (lane == 0) { snum[wave] = num; sden[wave] = den; }
    __syncthreads();

    if (threadIdx.x == 0) {
        float n2 = 0.0f, d2 = 0.0f;
#pragma unroll
        for (int w = 0; w < BLOCK / 64; ++w) { n2 += snum[w]; d2 += sden[w]; }
        ws[2 * bid + 0] = n2;
        ws[2 * bid + 1] = d2;
        __threadfence();               // make partial visible device-wide
    }

    // One grid barrier (execution + memory visibility across XCDs).
    cg::this_grid().sync();

    // Block 0 reduces the 512 pairs — identical order to the old fape_final.
    if (bid == 0) {
        float n = 0.0f, d = 0.0f;
        for (int i = threadIdx.x; i < NBLOCKS; i += BLOCK) {
            n += ws[2 * i + 0];
            d += ws[2 * i + 1];
        }
        for (int off = 32; off > 0; off >>= 1) {
            n += __shfl_down(n, off, 64);
            d += __shfl_down(d, off, 64);
        }
        __shared__ float sn[BLOCK / 64];
        __shared__ float sd[BLOCK / 64];
        if (lane == 0) { sn[wave] = n; sd[wave] = d; }
        __syncthreads();
        if (threadIdx.x == 0) {
            float nt = 0.0f, dt = 0.0f;
#pragma unroll
            for (int w = 0; w < BLOCK / 64; ++w) { nt += sn[w]; dt += sd[w]; }
            out[0] = nt / (dt + EPS_DIST_F);
        }
    }
}

extern "C" void kernel_launch(void* const* d_in, const int* in_sizes, int n_in,
                              void* d_out, int out_size, void* d_ws, size_t ws_size,
                              hipStream_t stream)
{
    const float* pred  = (const float*)d_in[0];
    const float* truec = (const float*)d_in[1];
    const float* mask  = (const float*)d_in[2];
    float* out = (float*)d_out;
    float* ws  = (float*)d_ws;   // NBLOCKS*2 floats, written before read

    dim3 grid(NBLK_X, BATCH);
    dim3 block(BLOCK);
    void* args[] = { (void*)&pred, (void*)&truec, (void*)&mask,
                     (void*)&ws, (void*)&out };
    hipLaunchCooperativeKernel((const void*)fape_coop, grid, block,
                               args, 0, stream);
}

// Round 5
// 70.127 us; speedup vs baseline: 1.8179x; 1.8179x over previous
//
#include <hip/hip_runtime.h>

#define BATCH 64
#define NPTS  4096
#define NFRAMES 100
#define BLOCK 256
#define PPT 4                          // consecutive points per thread
#define KSPAN (BLOCK * PPT)            // 1024
#define NBLK_X (NPTS / KSPAN)          // 4
#define NBLOCKS (BATCH * NBLK_X)       // 256
#define EPS_DIST_F 1e-8f

// R5: revert to the two-plain-dispatch structure (best measured: 68.4 us).
// R3 (atomic ticket, +16us) and R4 (grid.sync, +45us: fape_coop measured
// 52.6us wall @ 10.8% VALUBusy ~= 5.7us of real work) proved cross-block
// rendezvous costs far more than the dependent dispatch it replaces.
//
// Tightening vs R1: PPT=4 with CONSECUTIVE points per thread -> the 12
// coordinate floats per tensor are 48B contiguous = 3x global_load_dwordx4
// (16B/lane, perfectly coalesced); mask is one float4. LDS broadcast traffic
// per CU halves again (3 ds_read_b128 feed 16 evals). Grid = 256 blocks =
// 1 block/CU, 4 waves/CU.
//
// Math note: reference rotates diff by an orthonormal frame before the norm;
// rotation preserves the 2-norm, so distance = ||(pred_k - true_k) -
// (pred_f - true_f)||. Frame origins are the first NFRAMES points.
__global__ __launch_bounds__(BLOCK) void fape_main(
    const float* __restrict__ pred,
    const float* __restrict__ truec,
    const float* __restrict__ mask,
    float* __restrict__ partial)       // [NBLOCKS * 2] (num, den) per block
{
    __shared__ __align__(16) float sfx[NFRAMES];
    __shared__ __align__(16) float sfy[NFRAMES];
    __shared__ __align__(16) float sfz[NFRAMES];

    const int b  = blockIdx.y;
    const int k0 = blockIdx.x * KSPAN + threadIdx.x * PPT;  // multiple of 4

    const float* __restrict__ pb = pred  + (size_t)b * NPTS * 3;
    const float* __restrict__ tb = truec + (size_t)b * NPTS * 3;

    // 4 consecutive points = 12 floats = 48 B, 16B-aligned (3*k0 % 4 == 0).
    // Issue these global loads FIRST: latency drains under staging+barrier.
    const float4 pq0 = *(const float4*)&pb[3 * k0 + 0];
    const float4 pq1 = *(const float4*)&pb[3 * k0 + 4];
    const float4 pq2 = *(const float4*)&pb[3 * k0 + 8];
    const float4 tq0 = *(const float4*)&tb[3 * k0 + 0];
    const float4 tq1 = *(const float4*)&tb[3 * k0 + 4];
    const float4 tq2 = *(const float4*)&tb[3 * k0 + 8];
    const float4 mq  = *(const float4*)&mask[(size_t)b * NPTS + k0];

    // Stage frame deltas (origins f = coords[:, :-2] -> first 100 points).
    if (threadIdx.x < NFRAMES) {
        const int t = threadIdx.x;
        sfx[t] = pb[3 * t + 0] - tb[3 * t + 0];
        sfy[t] = pb[3 * t + 1] - tb[3 * t + 1];
        sfz[t] = pb[3 * t + 2] - tb[3 * t + 2];
    }
    __syncthreads();

    // Point deltas, unpacked from the three float4s (p0..p3 = points k0..k0+3).
    const float d0x = pq0.x - tq0.x, d0y = pq0.y - tq0.y, d0z = pq0.z - tq0.z;
    const float d1x = pq0.w - tq0.w, d1y = pq1.x - tq1.x, d1z = pq1.y - tq1.y;
    const float d2x = pq1.z - tq1.z, d2y = pq1.w - tq1.w, d2z = pq2.x - tq2.x;
    const float d3x = pq2.y - tq2.y, d3y = pq2.z - tq2.z, d3z = pq2.w - tq2.w;

    float acc0 = 0.0f, acc1 = 0.0f, acc2 = 0.0f, acc3 = 0.0f;

#define EVAL(DX, DY, DZ, FX, FY, FZ, ACC) do {                                  \
        const float ex_ = (DX) - (FX);                                          \
        const float ey_ = (DY) - (FY);                                          \
        const float ez_ = (DZ) - (FZ);                                          \
        const float s_  = __builtin_fmaf(ex_, ex_,                              \
                          __builtin_fmaf(ey_, ey_,                              \
                          __builtin_fmaf(ez_, ez_, EPS_DIST_F)));               \
        (ACC) += fminf(__builtin_amdgcn_sqrtf(s_), 10.0f);                      \
    } while (0)

#define EVAL4(FX, FY, FZ) do {                                                  \
        EVAL(d0x, d0y, d0z, FX, FY, FZ, acc0);                                  \
        EVAL(d1x, d1y, d1z, FX, FY, FZ, acc1);                                  \
        EVAL(d2x, d2y, d2z, FX, FY, FZ, acc2);                                  \
        EVAL(d3x, d3y, d3z, FX, FY, FZ, acc3);                                  \
    } while (0)

#pragma unroll 2
    for (int f = 0; f < NFRAMES; f += 4) {
        const float4 fx = *(const float4*)&sfx[f];
        const float4 fy = *(const float4*)&sfy[f];
        const float4 fz = *(const float4*)&sfz[f];

        EVAL4(fx.x, fy.x, fz.x);
        EVAL4(fx.y, fy.y, fz.y);
        EVAL4(fx.z, fy.z, fz.z);
        EVAL4(fx.w, fy.w, fz.w);
    }
#undef EVAL4
#undef EVAL

    float num = (acc0 * mq.x + acc1 * mq.y + acc2 * mq.z + acc3 * mq.w) * 0.1f;
    float den = mq.x + mq.y + mq.z + mq.w;

    // Wave-64 shuffle reduction.
    for (int off = 32; off > 0; off >>= 1) {
        num += __shfl_down(num, off, 64);
        den += __shfl_down(den, off, 64);
    }

    __shared__ float snum[BLOCK / 64];
    __shared__ float sden[BLOCK / 64];
    const int wave = threadIdx.x >> 6;
    const int lane = threadIdx.x & 63;
    if (lane == 0) { snum[wave] = num; sden[wave] = den; }
    __syncthreads();

    if (threadIdx.x == 0) {
        float n2 = 0.0f, d2 = 0.0f;
#pragma unroll
        for (int w = 0; w < BLOCK / 64; ++w) { n2 += snum[w]; d2 += sden[w]; }
        const int bid = b * NBLK_X + blockIdx.x;
        partial[2 * bid + 0] = n2;
        partial[2 * bid + 1] = d2;
    }
}

// Reduce NBLOCKS partial pairs -> scalar. One block.
__global__ __launch_bounds__(BLOCK) void fape_final(
    const float* __restrict__ partial,
    float* __restrict__ out)
{
    float n = 0.0f, d = 0.0f;
    for (int i = threadIdx.x; i < NBLOCKS; i += BLOCK) {
        n += partial[2 * i + 0];
        d += partial[2 * i + 1];
    }
    for (int off = 32; off > 0; off >>= 1) {
        n += __shfl_down(n, off, 64);
        d += __shfl_down(d, off, 64);
    }
    __shared__ float sn[BLOCK / 64];
    __shared__ float sd[BLOCK / 64];
    const int wave = threadIdx.x >> 6;
    const int lane = threadIdx.x & 63;
    if (lane == 0) { sn[wave] = n; sd[wave] = d; }
    __syncthreads();
    if (threadIdx.x == 0) {
        float nt = 0.0f, dt = 0.0f;
#pragma unroll
        for (int w = 0; w < BLOCK / 64; ++w) { nt += sn[w]; dt += sd[w]; }
        out[0] = nt / (dt + EPS_DIST_F);
    }
}

extern "C" void kernel_launch(void* const* d_in, const int* in_sizes, int n_in,
                              void* d_out, int out_size, void* d_ws, size_t ws_size,
                              hipStream_t stream)
{
    const float* pred  = (const float*)d_in[0];
    const float* truec = (const float*)d_in[1];
    const float* mask  = (const float*)d_in[2];
    float* out = (float*)d_out;
    float* ws  = (float*)d_ws;   // partial sums: NBLOCKS * 2 floats (no init needed)

    dim3 grid(NBLK_X, BATCH);
    fape_main<<<grid, BLOCK, 0, stream>>>(pred, truec, mask, ws);
    fape_final<<<1, BLOCK, 0, stream>>>(ws, out);
}